// Round 16
// baseline (114.939 us; speedup 1.0000x reference)
//
#include <hip/hip_runtime.h>

#define B_ 2
#define S_ 2048
#define DM 1024
#define NH 16
#define DK 64

using bf16x8  = __attribute__((ext_vector_type(8)))  short;
using f32x4   = __attribute__((ext_vector_type(4)))  float;

__device__ __forceinline__ float bf2f(short v){
  unsigned u = ((unsigned)(unsigned short)v) << 16;
  union { unsigned u; float f; } c; c.u = u; return c.f;
}
__device__ __forceinline__ short f2bf(float f){
  union { float f; unsigned u; } c; c.f = f;
  unsigned u = c.u + 0x7FFFu + ((c.u >> 16) & 1u);
  return (short)(u >> 16);
}
// pack two f32 -> two bf16 (truncation) in one v_perm_b32
__device__ __forceinline__ unsigned packbf(float lo, float hi){
  union { float f; unsigned u; } a, b; a.f = lo; b.f = hi;
  return __builtin_amdgcn_perm(b.u, a.u, 0x07060302u);
}
__device__ __forceinline__ void gload16(const void* g, void* l){
  __builtin_amdgcn_global_load_lds(
    (const __attribute__((address_space(1))) unsigned*)g,
    (__attribute__((address_space(3))) unsigned*)l, 16, 0, 0);
}

// ---------------- merged cast (blocks 0..8191) + rope table (blocks 8192..8703) ----------------
__global__ void cast_rope(const float* __restrict__ x, const float* __restrict__ wq,
                          const float* __restrict__ wk, const float* __restrict__ wv,
                          const float* __restrict__ wo, const int* __restrict__ pos,
                          short* __restrict__ xb, short* __restrict__ wqkv,
                          short* __restrict__ wob, float* __restrict__ tab){
  const int bid = blockIdx.x;
  if (bid < 8192){
    int i = bid * 256 + threadIdx.x;   // float4 index, total 2M
    const float4* src; short4* dst;
    if (i < (1 << 20)){
      src = (const float4*)x + i; dst = (short4*)xb + i;
    } else {
      int j = i - (1 << 20);
      int seg = j >> 18, off = j & ((1 << 18) - 1);
      const float* sp = seg == 0 ? wq : seg == 1 ? wk : seg == 2 ? wv : wo;
      short* dp = seg < 3 ? wqkv + ((size_t)seg << 20) : wob;
      src = (const float4*)sp + off; dst = (short4*)dp + off;
    }
    float4 v = *src;
    short4 o; o.x = f2bf(v.x); o.y = f2bf(v.y); o.z = f2bf(v.z); o.w = f2bf(v.w);
    *dst = o;
  } else {
    int idx = (bid - 8192) * 256 + threadIdx.x;   // 0 .. 131071
    int j = idx & 31, bs = idx >> 5;
    float p = (float)pos[bs];
    float inv = powf(10000.0f, -(float)(2 * j) / 64.0f);
    float ang = p * inv;
    tab[(size_t)bs * 64 + j]      = cosf(ang);
    tab[(size_t)bs * 64 + 32 + j] = sinf(ang);
  }
}

// ---------------- GEMM1: 128x128 tile, 3-buffer counted-vmcnt pipeline ----------------
// XCD 2D-chunk mapping: each XCD owns 12 bn x 8 bm (B 3MB + A 2MB working set).
// Fused epilogues: Q/K blocks (bn<16) -> RoPE + head-reshape; V blocks (bn>=16) ->
// in-block LDS transpose -> Vt [b,h,d,s] coalesced.
__launch_bounds__(512)
__global__ void gemm_qkv(const short* __restrict__ A, const short* __restrict__ Bm,
                         const float* __restrict__ tab,
                         short* __restrict__ Qr, short* __restrict__ Kr,
                         short* __restrict__ Vt){
  __shared__ short lds[3 * 8192];
  constexpr int K = 1024, NT = 32;
  const int tid = threadIdx.x;
  const int l = tid & 63, w = tid >> 6;
  const int lr = l & 15, lg = l >> 4;
  const int wr = w >> 2, wc = w & 3;
  const int wg  = blockIdx.y * gridDim.x + blockIdx.x;   // 0..767
  const int xcd = wg & 7, idx = wg >> 3;                 // idx 0..95
  const int bn  = (xcd & 1) * 12 + idx % 12;             // 0..23
  const int bm  = (xcd >> 1) * 8 + idx / 12;             // 0..31
  const short* Ab = A  + (size_t)bm * 128 * K;
  const short* Bb = Bm + (size_t)bn * 128 * K;
  const int r0 = tid >> 2, c4 = tid & 3;
  f32x4 acc[4][2];
  #pragma unroll
  for (int m = 0; m < 4; ++m)
    #pragma unroll
    for (int n = 0; n < 2; ++n) acc[m][n] = (f32x4){0.f, 0.f, 0.f, 0.f};

  auto stage = [&](int t){
    short* buf = lds + (t % 3) * 8192;
    gload16(Ab + (size_t)r0 * K + t * 32 + c4 * 8, buf + tid * 8);
    gload16(Bb + (size_t)r0 * K + t * 32 + c4 * 8, buf + 4096 + tid * 8);
  };

  stage(0); stage(1);
  for (int t = 0; t < NT; ++t){
    if (t < NT - 1) asm volatile("s_waitcnt vmcnt(2)" ::: "memory");
    else            asm volatile("s_waitcnt vmcnt(0)" ::: "memory");
    __builtin_amdgcn_s_barrier();
    __builtin_amdgcn_sched_barrier(0);
    if (t + 2 < NT) stage(t + 2);
    const short* bufA = lds + (t % 3) * 8192;
    const short* bufB = bufA + 4096;
    bf16x8 a[4], bfr[2];
    #pragma unroll
    for (int m = 0; m < 4; ++m)
      a[m] = *(const bf16x8*)(bufA + (wr * 64 + m * 16 + lr) * 32 + lg * 8);
    #pragma unroll
    for (int n = 0; n < 2; ++n)
      bfr[n] = *(const bf16x8*)(bufB + (wc * 32 + n * 16 + lr) * 32 + lg * 8);
    __builtin_amdgcn_s_setprio(1);
    #pragma unroll
    for (int m = 0; m < 4; ++m)
      #pragma unroll
      for (int n = 0; n < 2; ++n)
        acc[m][n] = __builtin_amdgcn_mfma_f32_16x16x32_bf16(a[m], bfr[n], acc[m][n], 0, 0, 0);
    __builtin_amdgcn_s_setprio(0);
  }

  if (bn >= 16){
    // -------- V block: transpose via LDS, write Vt [b,h,d,s] coalesced --------
    __syncthreads();                       // staging buffers dead now
    short* T = lds;                        // T[col 128][row 136-padded]
    #pragma unroll
    for (int m = 0; m < 4; ++m)
      #pragma unroll
      for (int n = 0; n < 2; ++n){
        const int col_l = wc * 32 + n * 16 + lr;
        const int row0  = wr * 64 + m * 16 + lg * 4;
        short4 pk;
        pk.x = f2bf(acc[m][n][0]); pk.y = f2bf(acc[m][n][1]);
        pk.z = f2bf(acc[m][n][2]); pk.w = f2bf(acc[m][n][3]);
        *(short4*)(T + col_l * 136 + row0) = pk;
      }
    __syncthreads();
    const int h0   = (bn - 16) * 2;
    const int tok0 = bm * 128;
    const int b    = tok0 >> 11, s0 = tok0 & 2047;
    const int col_l = tid >> 2;
    const int d  = col_l & 63;
    const int hh = h0 + (col_l >> 6);
    short* dstrow = Vt + ((size_t)(b * NH + hh) * DK + d) * S_ + s0;
    #pragma unroll
    for (int k = 0; k < 4; ++k){
      const int chunk = (tid & 3) * 4 + k;   // 0..15, 8 s-values each
      bf16x8 v = *(const bf16x8*)(T + col_l * 136 + chunk * 8);
      *(bf16x8*)(dstrow + chunk * 8) = v;
    }
  } else {
    // -------- Q/K block: fused RoPE + head reshape --------
    #pragma unroll
    for (int m = 0; m < 4; ++m)
      #pragma unroll
      for (int n = 0; n < 2; ++n){
        const int col = bn * 128 + wc * 32 + n * 16 + lr;      // 0..2047
        const int which = col >> 10;                           // 0=Q, 1=K
        #pragma unroll
        for (int j = 0; j < 4; ++j){
          const int row = bm * 128 + wr * 64 + m * 16 + lg * 4 + j;   // token
          float v = acc[m][n][j];
          const int d  = col & 63;
          const int dp = d >> 1;
          const float c = tab[(size_t)row * 64 + dp];
          const float s = tab[(size_t)row * 64 + 32 + dp];
          const float p = __shfl_xor(v, 1);
          float r = v * c + p * ((d & 1) ? s : -s);
          if (which == 0) r *= 0.125f;
          short* dst = which ? Kr : Qr;
          const int b = row >> 11, si = row & 2047;
          const int h = (col >> 6) & 15;
          dst[(((size_t)(b * NH + h)) * S_ + si) * DK + d] = f2bf(r);
        }
      }
  }
}

// ---------------- GEMM2 (out-proj): 128x64 tile, grid 512 blocks (2/CU), fp32 out ----------------
__launch_bounds__(512)
__global__ void gemm_o(const short* __restrict__ A, const short* __restrict__ Bm,
                       float* __restrict__ C){
  __shared__ short As[128 * 32];
  __shared__ short Bs[64 * 32];
  constexpr int K = 1024, N = 1024;
  const int tid = threadIdx.x;
  const int l = tid & 63, w = tid >> 6;
  const int lr = l & 15, lg = l >> 4;
  const int wr = w >> 2, wc = w & 3;
  const int nwg = gridDim.x * gridDim.y;              // 512
  const int wg  = blockIdx.y * gridDim.x + blockIdx.x;
  const int sw  = (wg & 7) * (nwg >> 3) + (wg >> 3);
  const int bn  = sw % gridDim.x, bm = sw / gridDim.x;
  const short* Ab = A  + (size_t)bm * 128 * K;
  const short* Bb = Bm + (size_t)bn * 64 * K;
  f32x4 acc[4];
  #pragma unroll
  for (int m = 0; m < 4; ++m) acc[m] = (f32x4){0.f, 0.f, 0.f, 0.f};
  const int r0 = tid >> 2, c4 = tid & 3;
  for (int kt = 0; kt < K; kt += 32){
    gload16(Ab + (size_t)r0 * K + kt + c4 * 8, As + tid * 8);
    if (tid < 256)
      gload16(Bb + (size_t)r0 * K + kt + c4 * 8, Bs + tid * 8);
    __syncthreads();
    bf16x8 a[4], bfr;
    #pragma unroll
    for (int m = 0; m < 4; ++m)
      a[m] = *(const bf16x8*)(As + (wr * 64 + m * 16 + lr) * 32 + lg * 8);
    bfr = *(const bf16x8*)(Bs + (wc * 16 + lr) * 32 + lg * 8);
    #pragma unroll
    for (int m = 0; m < 4; ++m)
      acc[m] = __builtin_amdgcn_mfma_f32_16x16x32_bf16(a[m], bfr, acc[m], 0, 0, 0);
    __syncthreads();
  }
  #pragma unroll
  for (int m = 0; m < 4; ++m)
    #pragma unroll
    for (int j = 0; j < 4; ++j){
      int row = bm * 128 + wr * 64 + m * 16 + lg * 4 + j;
      int col = bn * 64 + wc * 16 + lr;
      C[(size_t)row * N + col] = acc[m][j];
    }
}

// ---------------- per-Q-tile step: swapped QK^T, in-register row softmax, defer-max ----------------
// Ks/Vs XOR-swizzled [64 rows][8 x 16B chunks]: global chunk c of row r at slot c ^ (r&7).
// Pw: per-wave [16 rows][32 u32] of packed bf16 P pairs, col swizzled by ((lr&7)<<2).
// T5: setprio(1) around the MFMA clusters (phase-diverse blocks on each CU -> scheduler leverage).
__device__ __forceinline__ void attn_tile_step(
    const bf16x8 qa0, const bf16x8 qa1,
    f32x4 (&acc)[4], float& mrow, float& lsum,
    const short* Ks, const short* Vs, unsigned* pw,
    int diagmask, int lr, int lg, int wl){
  float sv[4][4];
  __builtin_amdgcn_s_setprio(1);
  #pragma unroll
  for (int n = 0; n < 4; ++n){
    const int R = n * 16 + lr;
    const int c0 = lg ^ (R & 7);
    bf16x8 k0 = *(const bf16x8*)(Ks + R * 64 + c0 * 8);
    bf16x8 k1 = *(const bf16x8*)(Ks + R * 64 + (c0 ^ 4) * 8);
    f32x4 z = (f32x4){0.f, 0.f, 0.f, 0.f};
    z = __builtin_amdgcn_mfma_f32_16x16x32_bf16(k0, qa0, z, 0, 0, 0);   // S^T tile
    z = __builtin_amdgcn_mfma_f32_16x16x32_bf16(k1, qa1, z, 0, 0, 0);
    #pragma unroll
    for (int j = 0; j < 4; ++j) sv[n][j] = z[j];   // sv[n][j] = S[q=wl*16+lr][k=n*16+lg*4+j]
  }
  __builtin_amdgcn_s_setprio(0);
  if (diagmask){
    const int qloc = wl * 16 + lr;
    #pragma unroll
    for (int n = 0; n < 4; ++n)
      #pragma unroll
      for (int j = 0; j < 4; ++j)
        if (n * 16 + lg * 4 + j > qloc) sv[n][j] = -1e30f;
  }
  // row softmax: lane owns one q-row; combine over lg groups (xor 16, 32)
  float lm = sv[0][0];
  #pragma unroll
  for (int n = 0; n < 4; ++n)
    #pragma unroll
    for (int j = 0; j < 4; ++j) lm = fmaxf(lm, sv[n][j]);
  lm = fmaxf(lm, __shfl_xor(lm, 16));
  lm = fmaxf(lm, __shfl_xor(lm, 32));
  // defer-max (T13): skip rescale while tile max stays within +8 of running max
  if (!__all(lm <= mrow + 8.f)){
    float mnew = fmaxf(mrow, lm);
    float corr = __expf(mrow - mnew);
    mrow = mnew;
    lsum *= corr;
    float cb[4];
    #pragma unroll
    for (int j = 0; j < 4; ++j) cb[j] = __shfl(corr, lg * 4 + j);
    #pragma unroll
    for (int n = 0; n < 4; ++n)
      #pragma unroll
      for (int j = 0; j < 4; ++j) acc[n][j] *= cb[j];
  }
  float psum = 0.f;
  #pragma unroll
  for (int n = 0; n < 4; ++n)
    #pragma unroll
    for (int j = 0; j < 4; ++j){
      float p = __expf(sv[n][j] - mrow);
      sv[n][j] = p; psum += p;
    }
  psum += __shfl_xor(psum, 16);
  psum += __shfl_xor(psum, 32);
  lsum += psum;
  // pack P (bf16 pairs) -> per-wave LDS, reread as PV A-fragments (row-local, swizzled)
  const int swz = (lr & 7) << 2;
  #pragma unroll
  for (int n = 0; n < 4; ++n){
    pw[lr * 32 + ((n * 8 + lg * 2 + 0) ^ swz)] = packbf(sv[n][0], sv[n][1]);
    pw[lr * 32 + ((n * 8 + lg * 2 + 1) ^ swz)] = packbf(sv[n][2], sv[n][3]);
  }
  bf16x8 pa0 = *(const bf16x8*)(pw + lr * 32 + ((lg * 4) ^ swz));        // k 0..31
  bf16x8 pa1 = *(const bf16x8*)(pw + lr * 32 + ((16 + lg * 4) ^ swz));   // k 32..63
  __builtin_amdgcn_s_setprio(1);
  #pragma unroll
  for (int n = 0; n < 4; ++n){
    const int R = n * 16 + lr;
    const int c0 = lg ^ (R & 7);
    bf16x8 v0 = *(const bf16x8*)(Vs + R * 64 + c0 * 8);
    bf16x8 v1 = *(const bf16x8*)(Vs + R * 64 + (c0 ^ 4) * 8);
    acc[n] = __builtin_amdgcn_mfma_f32_16x16x32_bf16(pa0, v0, acc[n], 0, 0, 0);
    acc[n] = __builtin_amdgcn_mfma_f32_16x16x32_bf16(pa1, v1, acc[n], 0, 0, 0);
  }
  __builtin_amdgcn_s_setprio(0);
}

// ---------------- flash attention: paired Q-tiles (qt, 31-qt) on separate wave-groups ----------------
// 512 threads: waves 0-3 own tile t1 = 31-qp, waves 4-7 own tile t0 = qp. Shared K/V staging.
// Grid: 512 linear blocks, XCD-locality remap: all 16 qp-blocks of one bh land on one XCD
// (bid = (qp*4 + bh/8)*8 + bh%8, dispatch round-robins bid%8 across XCDs).
__launch_bounds__(512)
__global__ void attn_kernel(const short* __restrict__ Qr, const short* __restrict__ Kr,
                            const short* __restrict__ Vt, short* __restrict__ AO){
  __shared__ short Ks[2][64 * 64];
  __shared__ short Vs[2][64 * 64];   // [d][kk]
  __shared__ unsigned Pw[8][16 * 32];
  const int tid = threadIdx.x;
  const int l = tid & 63, w = tid >> 6;
  const int lr = l & 15, lg = l >> 4;
  const int wl = w & 3, wgp = w >> 2;
  const int bid = blockIdx.x;
  const int qp = bid >> 5;                       // 0..15
  const int bh = (((bid >> 3) & 3) << 3) | (bid & 7);   // 0..31, bh%8 == XCD
  const int h = bh & 15, b = bh >> 4;
  const int t0 = qp, t1 = 31 - qp;           // t0 in 0..15, t1 in 16..31
  const int myqt = wgp ? t0 : t1;
  const short* Qp = Qr + (size_t)bh * S_ * DK;
  const short* Kp = Kr + (size_t)bh * S_ * DK;
  const short* Vp = Vt + (size_t)bh * DK * S_;

  bf16x8 qa0, qa1;
  {
    const short* q0 = Qp + (size_t)(myqt * 64 + wl * 16 + lr) * DK + lg * 8;
    qa0 = *(const bf16x8*)q0; qa1 = *(const bf16x8*)(q0 + 32);
  }
  f32x4 acc[4];
  float ms = -1e30f, ls = 0.f;
  #pragma unroll
  for (int n = 0; n < 4; ++n) acc[n] = (f32x4){0.f, 0.f, 0.f, 0.f};
  unsigned* pw = &Pw[w][0];
  const int r0 = tid >> 3, q8 = tid & 7;          // staging: [64 rows][8 x 16B chunks], 512 threads
  const int sq8 = q8 ^ (r0 & 7);                  // pre-swizzled source chunk (rule #21)

  // prologue: stage tile 0 into buffer 0
  gload16(Kp + (size_t)r0 * DK + sq8 * 8, &Ks[0][tid * 8]);
  gload16(Vp + (size_t)r0 * S_ + sq8 * 8, &Vs[0][tid * 8]);
  int cur = 0;
  for (int kt = 0; kt <= t1; ++kt){
    __syncthreads();   // drains vmcnt: buf[cur] ready; all waves done reading buf[cur^1]
    if (kt < t1){
      gload16(Kp + (size_t)((kt + 1) * 64 + r0) * DK + sq8 * 8, &Ks[cur ^ 1][tid * 8]);
      gload16(Vp + (size_t)r0 * S_ + (kt + 1) * 64 + sq8 * 8,   &Vs[cur ^ 1][tid * 8]);
    }
    if (kt <= myqt)
      attn_tile_step(qa0, qa1, acc, ms, ls, Ks[cur], Vs[cur], pw, kt == myqt, lr, lg, wl);
    cur ^= 1;
  }
  const float li = 1.f / ls;
  #pragma unroll
  for (int j = 0; j < 4; ++j){
    const float d0 = __shfl(li, lg * 4 + j);
    #pragma unroll
    for (int n = 0; n < 4; ++n){
      int e = h * 64 + n * 16 + lr;
      int r = myqt * 64 + wl * 16 + lg * 4 + j;
      AO[((size_t)b * S_ + r) * DM + e] = f2bf(acc[n][j] * d0);
    }
  }
}

extern "C" void kernel_launch(void* const* d_in, const int* in_sizes, int n_in,
                              void* d_out, int out_size, void* d_ws, size_t ws_size,
                              hipStream_t stream){
  const float* x  = (const float*)d_in[0];
  const float* wq = (const float*)d_in[1];
  const float* wk = (const float*)d_in[2];
  const float* wv = (const float*)d_in[3];
  const float* wo = (const float*)d_in[4];
  const int*  pos = (const int*)d_in[5];

  char* ws = (char*)d_ws;
  short* xb   = (short*)(ws + 0);                       // 8 MB  [4096][1024] bf16 x
  short* wqkv = (short*)(ws + ((size_t)8  << 20));      // 6 MB  [3072][1024] bf16 (wq|wk|wv)
  short* wob  = (short*)(ws + ((size_t)14 << 20));      // 2 MB  [1024][1024]
  short* Qr   = (short*)(ws + ((size_t)40 << 20));      // 8 MB  [b,h,s,d]
  short* Kr   = (short*)(ws + ((size_t)48 << 20));      // 8 MB  [b,h,s,d]
  short* Vt   = (short*)(ws + ((size_t)56 << 20));      // 8 MB  [b,h,d,s]
  float* tab  = (float*)(ws + ((size_t)64 << 20));      // 1 MB  rope table
  short* AO   = xb;                                     // reuse xb (dead after GEMM1)
  float* out  = (float*)d_out;

  cast_rope<<<dim3(8704), dim3(256), 0, stream>>>(x, wq, wk, wv, wo, pos, xb, wqkv, wob, tab);
  gemm_qkv<<<dim3(24, 32), dim3(512), 0, stream>>>(xb, wqkv, tab, Qr, Kr, Vt);
  attn_kernel<<<dim3(512), dim3(512), 0, stream>>>(Qr, Kr, Vt, AO);
  gemm_o<<<dim3(16, 32), dim3(512), 0, stream>>>(AO, wob, out);
}

// Round 17
// 110.626 us; speedup vs baseline: 1.0390x; 1.0390x over previous
//
#include <hip/hip_runtime.h>

#define B_ 2
#define S_ 2048
#define DM 1024
#define NH 16
#define DK 64

using bf16x8  = __attribute__((ext_vector_type(8)))  short;
using f32x4   = __attribute__((ext_vector_type(4)))  float;

__device__ __forceinline__ float bf2f(short v){
  unsigned u = ((unsigned)(unsigned short)v) << 16;
  union { unsigned u; float f; } c; c.u = u; return c.f;
}
__device__ __forceinline__ short f2bf(float f){
  union { float f; unsigned u; } c; c.f = f;
  unsigned u = c.u + 0x7FFFu + ((c.u >> 16) & 1u);
  return (short)(u >> 16);
}
// pack two f32 -> two bf16 (truncation) in one v_perm_b32
__device__ __forceinline__ unsigned packbf(float lo, float hi){
  union { float f; unsigned u; } a, b; a.f = lo; b.f = hi;
  return __builtin_amdgcn_perm(b.u, a.u, 0x07060302u);
}
__device__ __forceinline__ void gload16(const void* g, void* l){
  __builtin_amdgcn_global_load_lds(
    (const __attribute__((address_space(1))) unsigned*)g,
    (__attribute__((address_space(3))) unsigned*)l, 16, 0, 0);
}

// ---------------- merged cast (blocks 0..8191) + rope table (blocks 8192..8703) ----------------
__global__ void cast_rope(const float* __restrict__ x, const float* __restrict__ wq,
                          const float* __restrict__ wk, const float* __restrict__ wv,
                          const float* __restrict__ wo, const int* __restrict__ pos,
                          short* __restrict__ xb, short* __restrict__ wqkv,
                          short* __restrict__ wob, float* __restrict__ tab){
  const int bid = blockIdx.x;
  if (bid < 8192){
    int i = bid * 256 + threadIdx.x;   // float4 index, total 2M
    const float4* src; short4* dst;
    if (i < (1 << 20)){
      src = (const float4*)x + i; dst = (short4*)xb + i;
    } else {
      int j = i - (1 << 20);
      int seg = j >> 18, off = j & ((1 << 18) - 1);
      const float* sp = seg == 0 ? wq : seg == 1 ? wk : seg == 2 ? wv : wo;
      short* dp = seg < 3 ? wqkv + ((size_t)seg << 20) : wob;
      src = (const float4*)sp + off; dst = (short4*)dp + off;
    }
    float4 v = *src;
    short4 o; o.x = f2bf(v.x); o.y = f2bf(v.y); o.z = f2bf(v.z); o.w = f2bf(v.w);
    *dst = o;
  } else {
    int idx = (bid - 8192) * 256 + threadIdx.x;   // 0 .. 131071
    int j = idx & 31, bs = idx >> 5;
    float p = (float)pos[bs];
    float inv = powf(10000.0f, -(float)(2 * j) / 64.0f);
    float ang = p * inv;
    tab[(size_t)bs * 64 + j]      = cosf(ang);
    tab[(size_t)bs * 64 + 32 + j] = sinf(ang);
  }
}

// ---------------- GEMM1: 128x128 tile, 3-buffer counted-vmcnt pipeline ----------------
// XCD 2D-chunk mapping: each XCD owns 12 bn x 8 bm (B 3MB + A 2MB working set).
// Fused epilogues: Q/K blocks (bn<16) -> RoPE + head-reshape; V blocks (bn>=16) ->
// in-block LDS transpose -> Vt [b,h,d,s] coalesced.
__launch_bounds__(512)
__global__ void gemm_qkv(const short* __restrict__ A, const short* __restrict__ Bm,
                         const float* __restrict__ tab,
                         short* __restrict__ Qr, short* __restrict__ Kr,
                         short* __restrict__ Vt){
  __shared__ short lds[3 * 8192];
  constexpr int K = 1024, NT = 32;
  const int tid = threadIdx.x;
  const int l = tid & 63, w = tid >> 6;
  const int lr = l & 15, lg = l >> 4;
  const int wr = w >> 2, wc = w & 3;
  const int wg  = blockIdx.y * gridDim.x + blockIdx.x;   // 0..767
  const int xcd = wg & 7, idx = wg >> 3;                 // idx 0..95
  const int bn  = (xcd & 1) * 12 + idx % 12;             // 0..23
  const int bm  = (xcd >> 1) * 8 + idx / 12;             // 0..31
  const short* Ab = A  + (size_t)bm * 128 * K;
  const short* Bb = Bm + (size_t)bn * 128 * K;
  const int r0 = tid >> 2, c4 = tid & 3;
  f32x4 acc[4][2];
  #pragma unroll
  for (int m = 0; m < 4; ++m)
    #pragma unroll
    for (int n = 0; n < 2; ++n) acc[m][n] = (f32x4){0.f, 0.f, 0.f, 0.f};

  auto stage = [&](int t){
    short* buf = lds + (t % 3) * 8192;
    gload16(Ab + (size_t)r0 * K + t * 32 + c4 * 8, buf + tid * 8);
    gload16(Bb + (size_t)r0 * K + t * 32 + c4 * 8, buf + 4096 + tid * 8);
  };

  stage(0); stage(1);
  for (int t = 0; t < NT; ++t){
    if (t < NT - 1) asm volatile("s_waitcnt vmcnt(2)" ::: "memory");
    else            asm volatile("s_waitcnt vmcnt(0)" ::: "memory");
    __builtin_amdgcn_s_barrier();
    __builtin_amdgcn_sched_barrier(0);
    if (t + 2 < NT) stage(t + 2);
    const short* bufA = lds + (t % 3) * 8192;
    const short* bufB = bufA + 4096;
    bf16x8 a[4], bfr[2];
    #pragma unroll
    for (int m = 0; m < 4; ++m)
      a[m] = *(const bf16x8*)(bufA + (wr * 64 + m * 16 + lr) * 32 + lg * 8);
    #pragma unroll
    for (int n = 0; n < 2; ++n)
      bfr[n] = *(const bf16x8*)(bufB + (wc * 32 + n * 16 + lr) * 32 + lg * 8);
    __builtin_amdgcn_s_setprio(1);
    #pragma unroll
    for (int m = 0; m < 4; ++m)
      #pragma unroll
      for (int n = 0; n < 2; ++n)
        acc[m][n] = __builtin_amdgcn_mfma_f32_16x16x32_bf16(a[m], bfr[n], acc[m][n], 0, 0, 0);
    __builtin_amdgcn_s_setprio(0);
  }

  if (bn >= 16){
    // -------- V block: transpose via LDS, write Vt [b,h,d,s] coalesced --------
    __syncthreads();                       // staging buffers dead now
    short* T = lds;                        // T[col 128][row 136-padded]
    #pragma unroll
    for (int m = 0; m < 4; ++m)
      #pragma unroll
      for (int n = 0; n < 2; ++n){
        const int col_l = wc * 32 + n * 16 + lr;
        const int row0  = wr * 64 + m * 16 + lg * 4;
        short4 pk;
        pk.x = f2bf(acc[m][n][0]); pk.y = f2bf(acc[m][n][1]);
        pk.z = f2bf(acc[m][n][2]); pk.w = f2bf(acc[m][n][3]);
        *(short4*)(T + col_l * 136 + row0) = pk;
      }
    __syncthreads();
    const int h0   = (bn - 16) * 2;
    const int tok0 = bm * 128;
    const int b    = tok0 >> 11, s0 = tok0 & 2047;
    const int col_l = tid >> 2;
    const int d  = col_l & 63;
    const int hh = h0 + (col_l >> 6);
    short* dstrow = Vt + ((size_t)(b * NH + hh) * DK + d) * S_ + s0;
    #pragma unroll
    for (int k = 0; k < 4; ++k){
      const int chunk = (tid & 3) * 4 + k;   // 0..15, 8 s-values each
      bf16x8 v = *(const bf16x8*)(T + col_l * 136 + chunk * 8);
      *(bf16x8*)(dstrow + chunk * 8) = v;
    }
  } else {
    // -------- Q/K block: fused RoPE + head reshape --------
    #pragma unroll
    for (int m = 0; m < 4; ++m)
      #pragma unroll
      for (int n = 0; n < 2; ++n){
        const int col = bn * 128 + wc * 32 + n * 16 + lr;      // 0..2047
        const int which = col >> 10;                           // 0=Q, 1=K
        #pragma unroll
        for (int j = 0; j < 4; ++j){
          const int row = bm * 128 + wr * 64 + m * 16 + lg * 4 + j;   // token
          float v = acc[m][n][j];
          const int d  = col & 63;
          const int dp = d >> 1;
          const float c = tab[(size_t)row * 64 + dp];
          const float s = tab[(size_t)row * 64 + 32 + dp];
          const float p = __shfl_xor(v, 1);
          float r = v * c + p * ((d & 1) ? s : -s);
          if (which == 0) r *= 0.125f;
          short* dst = which ? Kr : Qr;
          const int b = row >> 11, si = row & 2047;
          const int h = (col >> 6) & 15;
          dst[(((size_t)(b * NH + h)) * S_ + si) * DK + d] = f2bf(r);
        }
      }
  }
}

// ---------------- GEMM2 (out-proj): 128x64 tile, 3-buffer counted-vmcnt pipeline, fp32 out ----------------
// Per stage: waves 0-3 load A-chunk + B-chunk (vmcnt(2) steady), waves 4-7 A-chunk only (vmcnt(1)).
__launch_bounds__(512)
__global__ void gemm_o(const short* __restrict__ A, const short* __restrict__ Bm,
                       float* __restrict__ C){
  __shared__ short lds[3 * 6144];   // per buffer: A[128][32] (4096) | B[64][32] (2048)
  constexpr int K = 1024, N = 1024, NT = 32;
  const int tid = threadIdx.x;
  const int l = tid & 63, w = tid >> 6;
  const int lr = l & 15, lg = l >> 4;
  const int wr = w >> 2, wc = w & 3;
  const int nwg = gridDim.x * gridDim.y;              // 512
  const int wg  = blockIdx.y * gridDim.x + blockIdx.x;
  const int sw  = (wg & 7) * (nwg >> 3) + (wg >> 3);
  const int bn  = sw % gridDim.x, bm = sw / gridDim.x;
  const short* Ab = A  + (size_t)bm * 128 * K;
  const short* Bb = Bm + (size_t)bn * 64 * K;
  const int r0 = tid >> 2, c4 = tid & 3;
  f32x4 acc[4];
  #pragma unroll
  for (int m = 0; m < 4; ++m) acc[m] = (f32x4){0.f, 0.f, 0.f, 0.f};

  auto stage = [&](int t){
    short* buf = lds + (t % 3) * 6144;
    gload16(Ab + (size_t)r0 * K + t * 32 + c4 * 8, buf + tid * 8);
    if (tid < 256)
      gload16(Bb + (size_t)r0 * K + t * 32 + c4 * 8, buf + 4096 + tid * 8);
  };

  stage(0); stage(1);
  for (int t = 0; t < NT; ++t){
    if (t < NT - 1){
      if (tid < 256) asm volatile("s_waitcnt vmcnt(2)" ::: "memory");
      else           asm volatile("s_waitcnt vmcnt(1)" ::: "memory");
    } else           asm volatile("s_waitcnt vmcnt(0)" ::: "memory");
    __builtin_amdgcn_s_barrier();
    __builtin_amdgcn_sched_barrier(0);
    if (t + 2 < NT) stage(t + 2);
    const short* bufA = lds + (t % 3) * 6144;
    const short* bufB = bufA + 4096;
    bf16x8 a[4], bfr;
    #pragma unroll
    for (int m = 0; m < 4; ++m)
      a[m] = *(const bf16x8*)(bufA + (wr * 64 + m * 16 + lr) * 32 + lg * 8);
    bfr = *(const bf16x8*)(bufB + (wc * 16 + lr) * 32 + lg * 8);
    __builtin_amdgcn_s_setprio(1);
    #pragma unroll
    for (int m = 0; m < 4; ++m)
      acc[m] = __builtin_amdgcn_mfma_f32_16x16x32_bf16(a[m], bfr, acc[m], 0, 0, 0);
    __builtin_amdgcn_s_setprio(0);
  }
  #pragma unroll
  for (int m = 0; m < 4; ++m)
    #pragma unroll
    for (int j = 0; j < 4; ++j){
      int row = bm * 128 + wr * 64 + m * 16 + lg * 4 + j;
      int col = bn * 64 + wc * 16 + lr;
      C[(size_t)row * N + col] = acc[m][j];
    }
}

// ---------------- per-Q-tile step: swapped QK^T, in-register row softmax, defer-max ----------------
// Ks/Vs XOR-swizzled [64 rows][8 x 16B chunks]: global chunk c of row r at slot c ^ (r&7).
// Pw: per-wave [16 rows][32 u32] of packed bf16 P pairs, col swizzled by ((lr&7)<<2).
__device__ __forceinline__ void attn_tile_step(
    const bf16x8 qa0, const bf16x8 qa1,
    f32x4 (&acc)[4], float& mrow, float& lsum,
    const short* Ks, const short* Vs, unsigned* pw,
    int diagmask, int lr, int lg, int wl){
  float sv[4][4];
  #pragma unroll
  for (int n = 0; n < 4; ++n){
    const int R = n * 16 + lr;
    const int c0 = lg ^ (R & 7);
    bf16x8 k0 = *(const bf16x8*)(Ks + R * 64 + c0 * 8);
    bf16x8 k1 = *(const bf16x8*)(Ks + R * 64 + (c0 ^ 4) * 8);
    f32x4 z = (f32x4){0.f, 0.f, 0.f, 0.f};
    z = __builtin_amdgcn_mfma_f32_16x16x32_bf16(k0, qa0, z, 0, 0, 0);   // S^T tile
    z = __builtin_amdgcn_mfma_f32_16x16x32_bf16(k1, qa1, z, 0, 0, 0);
    #pragma unroll
    for (int j = 0; j < 4; ++j) sv[n][j] = z[j];   // sv[n][j] = S[q=wl*16+lr][k=n*16+lg*4+j]
  }
  if (diagmask){
    const int qloc = wl * 16 + lr;
    #pragma unroll
    for (int n = 0; n < 4; ++n)
      #pragma unroll
      for (int j = 0; j < 4; ++j)
        if (n * 16 + lg * 4 + j > qloc) sv[n][j] = -1e30f;
  }
  // row softmax: lane owns one q-row; combine over lg groups (xor 16, 32)
  float lm = sv[0][0];
  #pragma unroll
  for (int n = 0; n < 4; ++n)
    #pragma unroll
    for (int j = 0; j < 4; ++j) lm = fmaxf(lm, sv[n][j]);
  lm = fmaxf(lm, __shfl_xor(lm, 16));
  lm = fmaxf(lm, __shfl_xor(lm, 32));
  // defer-max (T13): skip rescale while tile max stays within +8 of running max
  if (!__all(lm <= mrow + 8.f)){
    float mnew = fmaxf(mrow, lm);
    float corr = __expf(mrow - mnew);
    mrow = mnew;
    lsum *= corr;
    float cb[4];
    #pragma unroll
    for (int j = 0; j < 4; ++j) cb[j] = __shfl(corr, lg * 4 + j);
    #pragma unroll
    for (int n = 0; n < 4; ++n)
      #pragma unroll
      for (int j = 0; j < 4; ++j) acc[n][j] *= cb[j];
  }
  float psum = 0.f;
  #pragma unroll
  for (int n = 0; n < 4; ++n)
    #pragma unroll
    for (int j = 0; j < 4; ++j){
      float p = __expf(sv[n][j] - mrow);
      sv[n][j] = p; psum += p;
    }
  psum += __shfl_xor(psum, 16);
  psum += __shfl_xor(psum, 32);
  lsum += psum;
  // pack P (bf16 pairs) -> per-wave LDS, reread as PV A-fragments (row-local, swizzled)
  const int swz = (lr & 7) << 2;
  #pragma unroll
  for (int n = 0; n < 4; ++n){
    pw[lr * 32 + ((n * 8 + lg * 2 + 0) ^ swz)] = packbf(sv[n][0], sv[n][1]);
    pw[lr * 32 + ((n * 8 + lg * 2 + 1) ^ swz)] = packbf(sv[n][2], sv[n][3]);
  }
  bf16x8 pa0 = *(const bf16x8*)(pw + lr * 32 + ((lg * 4) ^ swz));        // k 0..31
  bf16x8 pa1 = *(const bf16x8*)(pw + lr * 32 + ((16 + lg * 4) ^ swz));   // k 32..63
  #pragma unroll
  for (int n = 0; n < 4; ++n){
    const int R = n * 16 + lr;
    const int c0 = lg ^ (R & 7);
    bf16x8 v0 = *(const bf16x8*)(Vs + R * 64 + c0 * 8);
    bf16x8 v1 = *(const bf16x8*)(Vs + R * 64 + (c0 ^ 4) * 8);
    acc[n] = __builtin_amdgcn_mfma_f32_16x16x32_bf16(pa0, v0, acc[n], 0, 0, 0);
    acc[n] = __builtin_amdgcn_mfma_f32_16x16x32_bf16(pa1, v1, acc[n], 0, 0, 0);
  }
}

// ---------------- flash attention: paired Q-tiles (qt, 31-qt) on separate wave-groups ----------------
// 512 threads: waves 0-3 own tile t1 = 31-qp, waves 4-7 own tile t0 = qp. Shared K/V staging.
// Grid: 512 linear blocks, XCD-locality remap: all 16 qp-blocks of one bh land on one XCD
// (bid = (qp*4 + bh/8)*8 + bh%8, dispatch round-robins bid%8 across XCDs).
__launch_bounds__(512)
__global__ void attn_kernel(const short* __restrict__ Qr, const short* __restrict__ Kr,
                            const short* __restrict__ Vt, short* __restrict__ AO){
  __shared__ short Ks[2][64 * 64];
  __shared__ short Vs[2][64 * 64];   // [d][kk]
  __shared__ unsigned Pw[8][16 * 32];
  const int tid = threadIdx.x;
  const int l = tid & 63, w = tid >> 6;
  const int lr = l & 15, lg = l >> 4;
  const int wl = w & 3, wgp = w >> 2;
  const int bid = blockIdx.x;
  const int qp = bid >> 5;                       // 0..15
  const int bh = (((bid >> 3) & 3) << 3) | (bid & 7);   // 0..31, bh%8 == XCD
  const int h = bh & 15, b = bh >> 4;
  const int t0 = qp, t1 = 31 - qp;           // t0 in 0..15, t1 in 16..31
  const int myqt = wgp ? t0 : t1;
  const short* Qp = Qr + (size_t)bh * S_ * DK;
  const short* Kp = Kr + (size_t)bh * S_ * DK;
  const short* Vp = Vt + (size_t)bh * DK * S_;

  bf16x8 qa0, qa1;
  {
    const short* q0 = Qp + (size_t)(myqt * 64 + wl * 16 + lr) * DK + lg * 8;
    qa0 = *(const bf16x8*)q0; qa1 = *(const bf16x8*)(q0 + 32);
  }
  f32x4 acc[4];
  float ms = -1e30f, ls = 0.f;
  #pragma unroll
  for (int n = 0; n < 4; ++n) acc[n] = (f32x4){0.f, 0.f, 0.f, 0.f};
  unsigned* pw = &Pw[w][0];
  const int r0 = tid >> 3, q8 = tid & 7;          // staging: [64 rows][8 x 16B chunks], 512 threads
  const int sq8 = q8 ^ (r0 & 7);                  // pre-swizzled source chunk (rule #21)

  // prologue: stage tile 0 into buffer 0
  gload16(Kp + (size_t)r0 * DK + sq8 * 8, &Ks[0][tid * 8]);
  gload16(Vp + (size_t)r0 * S_ + sq8 * 8, &Vs[0][tid * 8]);
  int cur = 0;
  for (int kt = 0; kt <= t1; ++kt){
    __syncthreads();   // drains vmcnt: buf[cur] ready; all waves done reading buf[cur^1]
    if (kt < t1){
      gload16(Kp + (size_t)((kt + 1) * 64 + r0) * DK + sq8 * 8, &Ks[cur ^ 1][tid * 8]);
      gload16(Vp + (size_t)r0 * S_ + (kt + 1) * 64 + sq8 * 8,   &Vs[cur ^ 1][tid * 8]);
    }
    if (kt <= myqt)
      attn_tile_step(qa0, qa1, acc, ms, ls, Ks[cur], Vs[cur], pw, kt == myqt, lr, lg, wl);
    cur ^= 1;
  }
  const float li = 1.f / ls;
  #pragma unroll
  for (int j = 0; j < 4; ++j){
    const float d0 = __shfl(li, lg * 4 + j);
    #pragma unroll
    for (int n = 0; n < 4; ++n){
      int e = h * 64 + n * 16 + lr;
      int r = myqt * 64 + wl * 16 + lg * 4 + j;
      AO[((size_t)b * S_ + r) * DM + e] = f2bf(acc[n][j] * d0);
    }
  }
}

extern "C" void kernel_launch(void* const* d_in, const int* in_sizes, int n_in,
                              void* d_out, int out_size, void* d_ws, size_t ws_size,
                              hipStream_t stream){
  const float* x  = (const float*)d_in[0];
  const float* wq = (const float*)d_in[1];
  const float* wk = (const float*)d_in[2];
  const float* wv = (const float*)d_in[3];
  const float* wo = (const float*)d_in[4];
  const int*  pos = (const int*)d_in[5];

  char* ws = (char*)d_ws;
  short* xb   = (short*)(ws + 0);                       // 8 MB  [4096][1024] bf16 x
  short* wqkv = (short*)(ws + ((size_t)8  << 20));      // 6 MB  [3072][1024] bf16 (wq|wk|wv)
  short* wob  = (short*)(ws + ((size_t)14 << 20));      // 2 MB  [1024][1024]
  short* Qr   = (short*)(ws + ((size_t)40 << 20));      // 8 MB  [b,h,s,d]
  short* Kr   = (short*)(ws + ((size_t)48 << 20));      // 8 MB  [b,h,s,d]
  short* Vt   = (short*)(ws + ((size_t)56 << 20));      // 8 MB  [b,h,d,s]
  float* tab  = (float*)(ws + ((size_t)64 << 20));      // 1 MB  rope table
  short* AO   = xb;                                     // reuse xb (dead after GEMM1)
  float* out  = (float*)d_out;

  cast_rope<<<dim3(8704), dim3(256), 0, stream>>>(x, wq, wk, wv, wo, pos, xb, wqkv, wob, tab);
  gemm_qkv<<<dim3(24, 32), dim3(512), 0, stream>>>(xb, wqkv, tab, Qr, Kr, Vt);
  attn_kernel<<<dim3(512), dim3(512), 0, stream>>>(Qr, Kr, Vt, AO);
  gemm_o<<<dim3(16, 32), dim3(512), 0, stream>>>(AO, wob, out);
}